// Round 1
// baseline (594.258 us; speedup 1.0000x reference)
//
#include <hip/hip_runtime.h>
#include <math.h>

// Problem constants (B=16, N=128, D=64, T=96)
#define BN   2048   // B*N
#define BN2  4096   // 2*B*N
#define DD   64
#define TT   96
#define NCH  128    // N (series channel stride)
#define RPB  8      // rows per block
#define TPB  256
#define NBLK (BN2 / RPB)   // 512

__device__ __forceinline__ void smax_merge(float& m, float& s, float mo, float so) {
  float nm = fmaxf(m, mo);
  s = s * __expf(m - nm) + so * __expf(mo - nm);
  m = nm;
}

__global__ __launch_bounds__(TPB) void k_rows(
    const float* __restrict__ of, const float* __restrict__ af,
    const float* __restrict__ os, float2* __restrict__ part)
{
  __shared__ float fA[RPB][DD];   // feature rows of this block
  __shared__ float sP[RPB][TT];   // series rows (p = i mod 2048)
  __shared__ float redm[4][RPB], reds[4][RPB], redA[4][RPB], redB[4][RPB];
  __shared__ float redsl[4];
  __shared__ float rowloss[RPB];

  const int tid = threadIdx.x;
  const int i0 = blockIdx.x * RPB;
  const int p0 = i0 & (BN - 1);   // 2048 % RPB == 0 so no boundary crossing

  for (int idx = tid; idx < RPB * DD; idx += TPB) {
    int r = idx >> 6, d = idx & 63;
    int i = i0 + r;
    fA[r][d] = (i < BN) ? of[(size_t)i * DD + d] : af[(size_t)(i - BN) * DD + d];
  }
  for (int idx = tid; idx < RPB * TT; idx += TPB) {
    int r = idx / TT, t = idx - r * TT;
    int p = p0 + r;
    sP[r][t] = os[((size_t)(p >> 7) * TT + t) * NCH + (p & (NCH - 1))];
  }
  __syncthreads();

  float m[RPB], s[RPB], Aa[RPB], Bb[RPB];
#pragma unroll
  for (int r = 0; r < RPB; ++r) { m[r] = -1e30f; s[r] = 0.f; Aa[r] = 0.f; Bb[r] = 0.f; }
  float slsum = 0.f;

  for (int cb = 0; cb < BN; cb += TPB) {
    const int c = cb + tid;          // column in [0,2048); c2 = c + 2048
    // --- sim dots for both column halves against the 8 staged rows ---
    float acc0[RPB], acc1[RPB];
#pragma unroll
    for (int r = 0; r < RPB; ++r) { acc0[r] = 0.f; acc1[r] = 0.f; }
    const float4* pc0 = (const float4*)(of + (size_t)c * DD);
    const float4* pc1 = (const float4*)(af + (size_t)c * DD);
#pragma unroll
    for (int d4 = 0; d4 < DD / 4; ++d4) {
      float4 a = pc0[d4], b = pc1[d4];
#pragma unroll
      for (int r = 0; r < RPB; ++r) {
        float4 f = *(const float4*)(&fA[r][d4 * 4]);
        acc0[r] = fmaf(a.x, f.x, fmaf(a.y, f.y, fmaf(a.z, f.z, fmaf(a.w, f.w, acc0[r]))));
        acc1[r] = fmaf(b.x, f.x, fmaf(b.y, f.y, fmaf(b.z, f.z, fmaf(b.w, f.w, acc1[r]))));
      }
    }
    // --- series sq-distance for q = c (shared by both halves) ---
    float dq[RPB];
#pragma unroll
    for (int r = 0; r < RPB; ++r) dq[r] = 0.f;
    const float* sq = os + ((size_t)(c >> 7) * TT) * NCH + (c & (NCH - 1));
    for (int t = 0; t < TT; ++t) {
      float v = sq[(size_t)t * NCH];
#pragma unroll
      for (int r = 0; r < RPB; ++r) { float u = v - sP[r][t]; dq[r] = fmaf(u, u, dq[r]); }
    }
    float sl[RPB];
#pragma unroll
    for (int r = 0; r < RPB; ++r) sl[r] = 1.f / (1.f + __expf(0.5f * dq[r]));

    // --- accumulate both columns per row ---
#pragma unroll
    for (int half = 0; half < 2; ++half) {
      const int cc = c + half * BN;
#pragma unroll
      for (int r = 0; r < RPB; ++r) {
        const int i = i0 + r;
        const bool masked = (cc >= i - 2) && (cc <= i);   // sim cols i-2,i-1,i handled separately
        const float v = half ? acc1[r] : acc0[r];
        const float slv = sl[r];
        slsum += slv;                                      // mean_soft_label counts ALL columns
        const float vd = masked ? -INFINITY : v;
        smax_merge(m[r], s[r], vd, 1.f);
        if (!masked) { Aa[r] += slv; Bb[r] += v * slv; }
      }
    }
  }

  // --- butterfly reduce across the 64-lane wave ---
#pragma unroll
  for (int off = 32; off; off >>= 1) {
#pragma unroll
    for (int r = 0; r < RPB; ++r) {
      float mo = __shfl_xor(m[r], off);
      float so = __shfl_xor(s[r], off);
      smax_merge(m[r], s[r], mo, so);
      Aa[r] += __shfl_xor(Aa[r], off);
      Bb[r] += __shfl_xor(Bb[r], off);
    }
    slsum += __shfl_xor(slsum, off);
  }
  const int w = tid >> 6;
  if ((tid & 63) == 0) {
#pragma unroll
    for (int r = 0; r < RPB; ++r) { redm[w][r] = m[r]; reds[w][r] = s[r]; redA[w][r] = Aa[r]; redB[w][r] = Bb[r]; }
    redsl[w] = slsum;
  }
  __syncthreads();

  if (tid < RPB) {
    const int r = tid;
    float M = redm[0][r], S = reds[0][r], Av = redA[0][r], Bv = redB[0][r];
    for (int ww = 1; ww < 4; ++ww) {
      smax_merge(M, S, redm[ww][r], reds[ww][r]);
      Av += redA[ww][r]; Bv += redB[ww][r];
    }
    const int i = i0 + r;
    // special combined elements: drop[i][i-2] = sim[i][i-2]+sim[i][i-1],
    //                            drop[i][i-1] = sim[i][i-1]+sim[i][i]
    float sim_ii = 0.f;
    for (int d = 0; d < DD; ++d) sim_ii = fmaf(fA[r][d], fA[r][d], sim_ii);
    if (i >= 1) {
      const int rm1 = i - 1;
      const float* fp1 = (rm1 < BN) ? (of + (size_t)rm1 * DD) : (af + (size_t)(rm1 - BN) * DD);
      float sim_m1 = 0.f;
      for (int d = 0; d < DD; ++d) sim_m1 = fmaf(fA[r][d], fp1[d], sim_m1);
      const int q1 = rm1 & (BN - 1);
      const float* sq1 = os + ((size_t)(q1 >> 7) * TT) * NCH + (q1 & (NCH - 1));
      float dd1 = 0.f;
      for (int t = 0; t < TT; ++t) { float u = sq1[(size_t)t * NCH] - sP[r][t]; dd1 = fmaf(u, u, dd1); }
      const float sl_m1 = 1.f / (1.f + __expf(0.5f * dd1));
      const float e2 = sim_m1 + sim_ii;
      const float snd2 = sl_m1 + 0.5f;    // sl[i][i] = sigmoid(0) = 0.5 (dist[p][p]=0)
      smax_merge(M, S, e2, 1.f);
      Av += snd2; Bv += e2 * snd2;
      if (i >= 2) {
        const int rm2 = i - 2;
        const float* fp2 = (rm2 < BN) ? (of + (size_t)rm2 * DD) : (af + (size_t)(rm2 - BN) * DD);
        float sim_m2 = 0.f;
        for (int d = 0; d < DD; ++d) sim_m2 = fmaf(fA[r][d], fp2[d], sim_m2);
        const int q2 = rm2 & (BN - 1);
        const float* sq2 = os + ((size_t)(q2 >> 7) * TT) * NCH + (q2 & (NCH - 1));
        float dd2 = 0.f;
        for (int t = 0; t < TT; ++t) { float u = sq2[(size_t)t * NCH] - sP[r][t]; dd2 = fmaf(u, u, dd2); }
        const float sl_m2 = 1.f / (1.f + __expf(0.5f * dd2));
        const float e1 = sim_m2 + sim_m1;
        const float snd1 = sl_m2 + sl_m1;
        smax_merge(M, S, e1, 1.f);
        Av += snd1; Bv += e1 * snd1;
      }
    }
    const float lse = M + logf(S);
    rowloss[r] = lse * Av - Bv;   // sum over this row of logits*soft_nd
  }
  __syncthreads();
  if (tid == 0) {
    float L = 0.f;
#pragma unroll
    for (int r = 0; r < RPB; ++r) L += rowloss[r];
    float SLt = redsl[0] + redsl[1] + redsl[2] + redsl[3];
    part[blockIdx.x] = make_float2(L, SLt);
  }
}

__global__ __launch_bounds__(TPB) void k_final(const float2* __restrict__ part,
                                               float* __restrict__ out)
{
  __shared__ float sl_[TPB], sm_[TPB];
  const int tid = threadIdx.x;
  float L = 0.f, S = 0.f;
  for (int b = tid; b < NBLK; b += TPB) { L += part[b].x; S += part[b].y; }
  sl_[tid] = L; sm_[tid] = S;
  __syncthreads();
  for (int off = TPB / 2; off; off >>= 1) {
    if (tid < off) { sl_[tid] += sl_[tid + off]; sm_[tid] += sm_[tid + off]; }
    __syncthreads();
  }
  if (tid == 0) {
    out[0] = sl_[0] / (float)((long long)BN2 * (BN2 - 1));  // mean over 4096*4095
    out[1] = sm_[0] / (float)((long long)BN2 * BN2);        // mean over 4096^2
  }
}

extern "C" void kernel_launch(void* const* d_in, const int* in_sizes, int n_in,
                              void* d_out, int out_size, void* d_ws, size_t ws_size,
                              hipStream_t stream) {
  (void)in_sizes; (void)n_in; (void)out_size; (void)ws_size;
  const float* of = (const float*)d_in[0];   // original_feature  (16,128,64)
  const float* af = (const float*)d_in[1];   // augmented_feature (16,128,64)
  const float* os = (const float*)d_in[2];   // original_series   (16,96,128)
  // d_in[3] (augmented_series) is unused by the reference.
  float2* part = (float2*)d_ws;              // NBLK float2 partials (4 KB)
  k_rows<<<NBLK, TPB, 0, stream>>>(of, af, os, part);
  k_final<<<1, TPB, 0, stream>>>(part, (float*)d_out);
}